// Round 11
// baseline (329.820 us; speedup 1.0000x reference)
//
#include <hip/hip_runtime.h>
#include <hip/hip_fp16.h>

#define BLK 256
#define PBLK 1024                // k_part block size
#define BSHIFT 8                 // bucket span = 256 nodes
#define BSPAN 256
#define CAPSLOT 12288            // padded per-bucket slot (edges); mean ~8192, +45 sigma

static inline int cdiv(long a, int b) { return (int)((a + b - 1) / b); }

// cursor[b] = b * CAPSLOT
__global__ __launch_bounds__(BLK) void k_initcur(int* __restrict__ cursor, int nbk) {
    int i = blockIdx.x * BLK + threadIdx.x;
    if (i < nbk) cursor[i] = i * CAPSLOT;
}

// one-time weight transpose: Wt[k*Cout+co] = W[co*Cin+k] for layers 2,3,4
__global__ __launch_bounds__(BLK) void k_twist(const float* __restrict__ W2, const float* __restrict__ W3,
                                               const float* __restrict__ W4, float* __restrict__ Wt2,
                                               float* __restrict__ Wt3, float* __restrict__ Wt4) {
    int t = blockIdx.x * BLK + threadIdx.x;
    if (t < 512) {                       // 32x16
        int co = t % 32, k = t / 32;
        Wt2[k * 32 + co] = W2[co * 16 + k];
    } else if (t < 512 + 1536) {         // 48x32
        int u = t - 512; int co = u % 48, k = u / 48;
        Wt3[k * 48 + co] = W3[co * 32 + k];
    } else if (t < 512 + 1536 + 3072) {  // 64x48
        int u = t - 2048; int co = u % 64, k = u / 64;
        Wt4[k * 64 + co] = W4[co * 48 + k];
    }
}

// partition edges into padded coarse buckets; packed = (col & 255) << 17 | row   (row < 2^17)
__global__ __launch_bounds__(PBLK) void k_part(const int* __restrict__ row, const int* __restrict__ col,
                                               int* __restrict__ cursor, unsigned* __restrict__ bkt,
                                               int e, int nbk, int per_wg) {
    __shared__ int h[512];
    __shared__ int base_l[512];
    __shared__ int c2[512];
    for (int i = threadIdx.x; i < nbk; i += PBLK) { h[i] = 0; c2[i] = 0; }
    __syncthreads();
    int base = blockIdx.x * per_wg;
    int end = min(e, base + per_wg);
    for (int i = base + threadIdx.x; i < end; i += PBLK) atomicAdd(&h[col[i] >> BSHIFT], 1);
    __syncthreads();
    for (int i = threadIdx.x; i < nbk; i += PBLK) base_l[i] = h[i] ? atomicAdd(&cursor[i], h[i]) : 0;
    __syncthreads();
    for (int i = base + threadIdx.x; i < end; i += PBLK) {
        int c = col[i];
        int b = c >> BSHIFT;
        int slot = atomicAdd(&c2[b], 1);
        bkt[base_l[b] + slot] = ((unsigned)(c & (BSPAN - 1)) << 17) | (unsigned)row[i];
    }
}

// one WG per bucket: LDS counting sort -> coalesced srow (padded layout), colstart/cnt/dinv
__global__ __launch_bounds__(BLK) void k_bucket(const unsigned* __restrict__ bkt, const int* __restrict__ cursor,
                                                int* __restrict__ colstart, int* __restrict__ cntarr,
                                                int* __restrict__ srow, float* __restrict__ dinv, int n) {
    __shared__ int stage[CAPSLOT];   // 48 KB
    __shared__ int deg[BSPAN];
    __shared__ int pfx[BSPAN];
    int b = blockIdx.x;
    int eb = b * CAPSLOT;
    int ee = min(cursor[b], eb + CAPSLOT);
    int cnt = ee - eb;
    int n0 = b << BSHIFT;
    int nn = min(BSPAN, n - n0);
    for (int i = threadIdx.x; i < nn; i += BLK) deg[i] = 0;
    __syncthreads();
    for (int i = eb + threadIdx.x; i < ee; i += BLK) atomicAdd(&deg[bkt[i] >> 17], 1);
    __syncthreads();
    if (threadIdx.x == 0) {
        int acc = 0;
        for (int i = 0; i < nn; ++i) { pfx[i] = acc; acc += deg[i]; }
    }
    __syncthreads();
    for (int i = threadIdx.x; i < nn; i += BLK) {
        colstart[n0 + i] = eb + pfx[i];
        cntarr[n0 + i] = deg[i];
        dinv[n0 + i] = rsqrtf((float)(deg[i] + 1));   // +1 self-loop
    }
    __syncthreads();
    for (int i = eb + threadIdx.x; i < ee; i += BLK) {
        unsigned p = bkt[i];
        int s = atomicAdd(&pfx[p >> 17], 1);
        stage[s] = (int)(p & 0x1FFFFu);
    }
    __syncthreads();
    for (int i = threadIdx.x; i < cnt; i += BLK) srow[eb + i] = stage[i];  // coalesced
}

// xs3[i,c] = dinv[i] * x[i,c]
__global__ __launch_bounds__(BLK) void k_scale3(const float* __restrict__ x, const float* __restrict__ dinv,
                                                float* __restrict__ xs, int n) {
    int t = blockIdx.x * BLK + threadIdx.x;
    if (t >= n * 3) return;
    xs[t] = dinv[t / 3] * x[t];
}

// fused layer 1: 3-ch fp32 agg (thread per node) + 3->16 transform + fp16 prescaled output (chunk A0)
__global__ __launch_bounds__(BLK) void k_agg3tf(const int* __restrict__ colstart, const int* __restrict__ cntarr,
                                                const int* __restrict__ srow, const float* __restrict__ xs3,
                                                const float* __restrict__ dinv, const float* __restrict__ W,
                                                const float* __restrict__ bias, __half* __restrict__ xs_out, int n) {
    __shared__ float sW[48];
    __shared__ float sB[16];
    if (threadIdx.x < 48) sW[threadIdx.x] = W[threadIdx.x];
    if (threadIdx.x < 16) sB[threadIdx.x] = bias[threadIdx.x];
    __syncthreads();
    int node = blockIdx.x * BLK + threadIdx.x;
    if (node >= n) return;
    float a0 = xs3[node * 3], a1 = xs3[node * 3 + 1], a2 = xs3[node * 3 + 2];
    int jb = colstart[node], je = jb + cntarr[node];
    int j = jb;
    for (; j + 1 < je; j += 2) {
        const float* p0 = xs3 + (size_t)srow[j] * 3;
        const float* p1 = xs3 + (size_t)srow[j + 1] * 3;
        a0 += p0[0] + p1[0]; a1 += p0[1] + p1[1]; a2 += p0[2] + p1[2];
    }
    if (j < je) {
        const float* p = xs3 + (size_t)srow[j] * 3;
        a0 += p[0]; a1 += p[1]; a2 += p[2];
    }
    float d = dinv[node];
    float y0 = d * a0, y1 = d * a1, y2 = d * a2;
#pragma unroll
    for (int q = 0; q < 4; ++q) {
        float v[4];
#pragma unroll
        for (int jj = 0; jj < 4; ++jj) {
            int co = q * 4 + jj;
            float acc = sB[co] + y0 * sW[co * 3] + y1 * sW[co * 3 + 1] + y2 * sW[co * 3 + 2];
            v[jj] = d * fmaxf(acc, 0.0f);
        }
        __half2 h0 = __halves2half2(__float2half(v[0]), __float2half(v[1]));
        __half2 h1 = __halves2half2(__float2half(v[2]), __float2half(v[3]));
        uint2 u = make_uint2(*(unsigned*)&h0, *(unsigned*)&h1);
        ((uint2*)xs_out)[(size_t)node * 4 + q] = u;
    }
}

// fused layer 2 (C=16 in, 32 out): gather from compact 3.2MB chunk (L2-resident), LDS y, transform,
// write TWO 16-ch fp16 chunks (prescaled by dinv) for layer 3's split passes.
__global__ __launch_bounds__(256) void k_aggtf2(const int* __restrict__ colstart, const int* __restrict__ cntarr,
                                                const int* __restrict__ srow, const __half2* __restrict__ xs,
                                                const float* __restrict__ dinv, const float* __restrict__ Wt,
                                                const float* __restrict__ bias,
                                                __half* __restrict__ out0, __half* __restrict__ out1, int n) {
    constexpr int TPB = 256, LPN = 8, HC = 8, H2PL = 1, NPB = 32, QPN = 8, CP = 20;
    __shared__ __align__(16) float yb[NPB][CP];
    __shared__ __align__(16) float smWt[16 * 32];
    __shared__ __align__(16) float smB[32];
    for (int idx = threadIdx.x; idx < 16 * 32; idx += TPB) smWt[idx] = Wt[idx];
    if (threadIdx.x < 32) smB[threadIdx.x] = bias[threadIdx.x];

    int nl = threadIdx.x / LPN;
    int c0 = threadIdx.x % LPN;
    int node = blockIdx.x * NPB + nl;
    if (node < n) {
        float2 acc = __half22float2(xs[(size_t)node * HC + c0]);
        int jb = colstart[node], je = jb + cntarr[node];
        int j = jb;
        for (; j + 3 < je; j += 4) {
            int r0 = srow[j], r1 = srow[j + 1], r2 = srow[j + 2], r3 = srow[j + 3];
            float2 f0 = __half22float2(xs[(size_t)r0 * HC + c0]);
            float2 f1 = __half22float2(xs[(size_t)r1 * HC + c0]);
            float2 f2 = __half22float2(xs[(size_t)r2 * HC + c0]);
            float2 f3 = __half22float2(xs[(size_t)r3 * HC + c0]);
            acc.x += (f0.x + f1.x) + (f2.x + f3.x);
            acc.y += (f0.y + f1.y) + (f2.y + f3.y);
        }
        for (; j < je; ++j) {
            float2 f = __half22float2(xs[(size_t)srow[j] * HC + c0]);
            acc.x += f.x; acc.y += f.y;
        }
        float d = dinv[node];
        *(float2*)&yb[nl][c0 * 2] = make_float2(d * acc.x, d * acc.y);
    }
    __syncthreads();

    int base = blockIdx.x * NPB;
    for (int idx = threadIdx.x; idx < NPB * QPN; idx += TPB) {
        int nl2 = idx / QPN, q = idx % QPN;
        int nd = base + nl2;
        if (nd >= n) break;
        const float* yr = yb[nl2];
        float4 bb = ((const float4*)smB)[q];
        float a0 = bb.x, a1 = bb.y, a2 = bb.z, a3 = bb.w;
        const float4* wt = (const float4*)smWt;
#pragma unroll
        for (int k = 0; k < 16; ++k) {
            float yk = yr[k];
            float4 w = wt[k * QPN + q];
            a0 = fmaf(yk, w.x, a0); a1 = fmaf(yk, w.y, a1);
            a2 = fmaf(yk, w.z, a2); a3 = fmaf(yk, w.w, a3);
        }
        float d = dinv[nd];
        a0 = d * fmaxf(a0, 0.f); a1 = d * fmaxf(a1, 0.f);
        a2 = d * fmaxf(a2, 0.f); a3 = d * fmaxf(a3, 0.f);
        __half2 h0 = __halves2half2(__float2half(a0), __float2half(a1));
        __half2 h1 = __halves2half2(__float2half(a2), __float2half(a3));
        uint2 u = make_uint2(*(unsigned*)&h0, *(unsigned*)&h1);
        if (q < 4) ((uint2*)out0)[(size_t)nd * 4 + q] = u;
        else       ((uint2*)out1)[(size_t)nd * 4 + (q - 4)] = u;
    }
}

// 16-channel gather pass over a compact 3.2MB chunk (L2-resident): y16 = dinv*(self + sum) in fp16.
// LPN=4 lanes/node, each lane owns 2 consecutive half2 (8B). 8-edge unroll.
__global__ __launch_bounds__(256) void k_agg16(const int* __restrict__ colstart, const int* __restrict__ cntarr,
                                               const int* __restrict__ srow, const __half2* __restrict__ xs,
                                               const float* __restrict__ dinv, __half* __restrict__ y16, int n) {
    int t = blockIdx.x * 256 + threadIdx.x;
    int node = t >> 2, c0 = (t & 3) * 2;
    if (node >= n) return;
    const __half2* self = xs + (size_t)node * 8 + c0;
    float2 a0 = __half22float2(self[0]);
    float2 a1 = __half22float2(self[1]);
    int jb = colstart[node], je = jb + cntarr[node];
    int j = jb;
    for (; j + 7 < je; j += 8) {
        int r[8];
#pragma unroll
        for (int u = 0; u < 8; ++u) r[u] = srow[j + u];
#pragma unroll
        for (int u = 0; u < 8; ++u) {
            const __half2* p = xs + (size_t)r[u] * 8 + c0;
            float2 f0 = __half22float2(p[0]), f1 = __half22float2(p[1]);
            a0.x += f0.x; a0.y += f0.y; a1.x += f1.x; a1.y += f1.y;
        }
    }
    for (; j < je; ++j) {
        const __half2* p = xs + (size_t)srow[j] * 8 + c0;
        float2 f0 = __half22float2(p[0]), f1 = __half22float2(p[1]);
        a0.x += f0.x; a0.y += f0.y; a1.x += f1.x; a1.y += f1.y;
    }
    float d = dinv[node];
    __half2 h0 = __halves2half2(__float2half(d * a0.x), __float2half(d * a0.y));
    __half2 h1 = __halves2half2(__float2half(d * a1.x), __float2half(d * a1.y));
    uint2 u = make_uint2(*(unsigned*)&h0, *(unsigned*)&h1);
    ((uint2*)y16)[(size_t)node * 4 + (t & 3)] = u;
}

// layer-3 transform: y = [Y0|Y1] fp16 (2x16ch), 32 -> 48, out 3x16-ch fp16 chunks prescaled by dinv
__global__ __launch_bounds__(256) void k_tf32(const __half2* __restrict__ Y0, const __half2* __restrict__ Y1,
                                              const float* __restrict__ Wt, const float* __restrict__ bias,
                                              const float* __restrict__ dinv,
                                              __half* __restrict__ o0, __half* __restrict__ o1,
                                              __half* __restrict__ o2, int n) {
    constexpr int QPN = 12;
    __shared__ __align__(16) float smWt[32 * 48];
    __shared__ __align__(16) float smB[48];
    for (int idx = threadIdx.x; idx < 32 * 48; idx += 256) smWt[idx] = Wt[idx];
    if (threadIdx.x < 48) smB[threadIdx.x] = bias[threadIdx.x];
    __syncthreads();
    int t = blockIdx.x * 256 + threadIdx.x;
    int node = t / QPN, q = t % QPN;
    if (node >= n) return;
    float yr[32];
#pragma unroll
    for (int h = 0; h < 8; ++h) {
        float2 f = __half22float2(Y0[(size_t)node * 8 + h]);
        yr[h * 2] = f.x; yr[h * 2 + 1] = f.y;
    }
#pragma unroll
    for (int h = 0; h < 8; ++h) {
        float2 f = __half22float2(Y1[(size_t)node * 8 + h]);
        yr[16 + h * 2] = f.x; yr[16 + h * 2 + 1] = f.y;
    }
    float4 bb = ((const float4*)smB)[q];
    float a0 = bb.x, a1 = bb.y, a2 = bb.z, a3 = bb.w;
    const float4* wt = (const float4*)smWt;
#pragma unroll
    for (int k = 0; k < 32; ++k) {
        float yk = yr[k];
        float4 w = wt[k * QPN + q];
        a0 = fmaf(yk, w.x, a0); a1 = fmaf(yk, w.y, a1);
        a2 = fmaf(yk, w.z, a2); a3 = fmaf(yk, w.w, a3);
    }
    float d = dinv[node];
    a0 = d * fmaxf(a0, 0.f); a1 = d * fmaxf(a1, 0.f);
    a2 = d * fmaxf(a2, 0.f); a3 = d * fmaxf(a3, 0.f);
    __half2 h0 = __halves2half2(__float2half(a0), __float2half(a1));
    __half2 h1 = __halves2half2(__float2half(a2), __float2half(a3));
    uint2 u = make_uint2(*(unsigned*)&h0, *(unsigned*)&h1);
    __half* ochunk = (q < 4) ? o0 : (q < 8 ? o1 : o2);
    ((uint2*)ochunk)[(size_t)node * 4 + (q & 3)] = u;
}

// layer-4 transform: y = [Y0|Y1|Y2] fp16 (3x16ch), 48 -> 64, out H fp32 (relu, no prescale)
__global__ __launch_bounds__(256) void k_tf48(const __half2* __restrict__ Y0, const __half2* __restrict__ Y1,
                                              const __half2* __restrict__ Y2, const float* __restrict__ Wt,
                                              const float* __restrict__ bias, float* __restrict__ H, int n) {
    constexpr int QPN = 16;
    __shared__ __align__(16) float smWt[48 * 64];
    __shared__ __align__(16) float smB[64];
    for (int idx = threadIdx.x; idx < 48 * 64; idx += 256) smWt[idx] = Wt[idx];
    if (threadIdx.x < 64) smB[threadIdx.x] = bias[threadIdx.x];
    __syncthreads();
    int t = blockIdx.x * 256 + threadIdx.x;
    int node = t >> 4, q = t & 15;
    if (node >= n) return;
    float yr[48];
    const __half2* Ys[3] = {Y0, Y1, Y2};
#pragma unroll
    for (int ch = 0; ch < 3; ++ch) {
#pragma unroll
        for (int h = 0; h < 8; ++h) {
            float2 f = __half22float2(Ys[ch][(size_t)node * 8 + h]);
            yr[ch * 16 + h * 2] = f.x; yr[ch * 16 + h * 2 + 1] = f.y;
        }
    }
    float4 bb = ((const float4*)smB)[q];
    float a0 = bb.x, a1 = bb.y, a2 = bb.z, a3 = bb.w;
    const float4* wt = (const float4*)smWt;
#pragma unroll
    for (int k = 0; k < 48; ++k) {
        float yk = yr[k];
        float4 w = wt[k * QPN + q];
        a0 = fmaf(yk, w.x, a0); a1 = fmaf(yk, w.y, a1);
        a2 = fmaf(yk, w.z, a2); a3 = fmaf(yk, w.w, a3);
    }
    ((float4*)H)[(size_t)node * QPN + q] =
        make_float4(fmaxf(a0, 0.f), fmaxf(a1, 0.f), fmaxf(a2, 0.f), fmaxf(a3, 0.f));
}

// batch is sorted -> graph boundaries
__global__ __launch_bounds__(BLK) void k_gbound(const int* __restrict__ batch, int* __restrict__ gstart, int n) {
    int i = blockIdx.x * BLK + threadIdx.x;
    if (i >= n) return;
    int b = batch[i];
    int pb = (i == 0) ? -1 : batch[i - 1];
    for (int g = pb + 1; g <= b; ++g) gstart[g] = i;
    if (i == n - 1) {
        for (int g = b + 1; g <= 256; ++g) gstart[g] = n;
    }
}

__global__ __launch_bounds__(256) void k_pool(const float* __restrict__ h, const int* __restrict__ gstart,
                                              float* __restrict__ g) {
    int gr = blockIdx.x;
    int c = threadIdx.x & 63, s = threadIdx.x >> 6;
    int i0 = gstart[gr], i1 = gstart[gr + 1];
    float m = 0.0f;
    for (int i = i0 + s; i < i1; i += 4) m = fmaxf(m, h[(size_t)i * 64 + c]);
    __shared__ float sm[256];
    sm[threadIdx.x] = m;
    __syncthreads();
    if (s == 0) {
        m = fmaxf(fmaxf(sm[c], sm[64 + c]), fmaxf(sm[128 + c], sm[192 + c]));
        g[gr * 64 + c] = m;
    }
}

__global__ __launch_bounds__(BLK) void k_mlp1(const float* __restrict__ g, const float* __restrict__ W,
                                              const float* __restrict__ b, float* __restrict__ g2, int ng) {
    int t = blockIdx.x * BLK + threadIdx.x;
    if (t >= ng * 64) return;
    int gi = t >> 6, co = t & 63;
    const float* gv = g + (gi << 6);
    const float* ws = W + co * 64;
    float acc = b[co];
#pragma unroll
    for (int k = 0; k < 64; ++k) acc = fmaf(gv[k], ws[k], acc);
    g2[t] = fmaxf(acc, 0.0f);
}

__global__ __launch_bounds__(BLK) void k_mlp2(const float* __restrict__ g2, const float* __restrict__ W,
                                              const float* __restrict__ b, float* __restrict__ out, int ng) {
    int t = blockIdx.x * BLK + threadIdx.x;
    if (t >= ng * 10) return;
    int gi = t / 10, co = t % 10;
    const float* gv = g2 + (gi << 6);
    const float* ws = W + co * 64;
    float acc = b[co];
#pragma unroll
    for (int k = 0; k < 64; ++k) acc = fmaf(gv[k], ws[k], acc);
    out[t] = acc;
}

extern "C" void kernel_launch(void* const* d_in, const int* in_sizes, int n_in,
                              void* d_out, int out_size, void* d_ws, size_t ws_size,
                              hipStream_t stream) {
    const float* x     = (const float*)d_in[0];
    const int*   ei    = (const int*)d_in[1];
    const int*   batch = (const int*)d_in[2];
    const float *W1 = (const float*)d_in[4],  *b1 = (const float*)d_in[5];
    const float *W2 = (const float*)d_in[6],  *b2 = (const float*)d_in[7];
    const float *W3 = (const float*)d_in[8],  *b3 = (const float*)d_in[9];
    const float *W4 = (const float*)d_in[10], *b4 = (const float*)d_in[11];
    const float *L1w = (const float*)d_in[12], *L1b = (const float*)d_in[13];
    const float *L2w = (const float*)d_in[14], *L2b = (const float*)d_in[15];
    float* out = (float*)d_out;

    const int n  = in_sizes[0] / 3;   // 100000 (row ids fit 17 bits)
    const int e  = in_sizes[1] / 2;   // 3200000
    const int ng = 256;
    const int* row = ei;
    const int* col = ei + e;
    const int nbk = cdiv(n, BSPAN);   // 391 coarse buckets

    char* ws = (char*)d_ws;
    size_t off = 0;
    auto alloc = [&](size_t bytes) -> void* {
        void* p = ws + off;
        off += (bytes + 255) & ~(size_t)255;
        return p;
    };
    int*    colstart = (int*)alloc((size_t)n * 4);
    int*    cntarr   = (int*)alloc((size_t)n * 4);
    float*  dinv     = (float*)alloc((size_t)n * 4);
    int*    srow     = (int*)alloc((size_t)nbk * CAPSLOT * 4);   // 19.2 MB padded
    int*    cursor   = (int*)alloc(512 * 4);
    int*    gstart   = (int*)alloc(257 * 4);
    float*  Wt2      = (float*)alloc(512 * 4);
    float*  Wt3      = (float*)alloc(1536 * 4);
    float*  Wt4      = (float*)alloc(3072 * 4);
    float*  XS3      = (float*)alloc((size_t)n * 3 * 4);
    __half* A0       = (__half*)alloc((size_t)n * 16 * 2);   // layer2 gather input
    __half* B0       = (__half*)alloc((size_t)n * 16 * 2);   // layer3 chunks
    __half* B1       = (__half*)alloc((size_t)n * 16 * 2);
    __half* C0       = (__half*)alloc((size_t)n * 16 * 2);   // layer4 chunks
    __half* C1       = (__half*)alloc((size_t)n * 16 * 2);
    __half* C2       = (__half*)alloc((size_t)n * 16 * 2);
    __half* Y0       = (__half*)alloc((size_t)n * 16 * 2);   // agg outputs (fp16)
    __half* Y1       = (__half*)alloc((size_t)n * 16 * 2);
    __half* Y2       = (__half*)alloc((size_t)n * 16 * 2);
    float*  H        = (float*)alloc((size_t)n * 64 * 4);
    float*  G        = (float*)alloc((size_t)ng * 64 * 4);
    float*  G2       = (float*)alloc((size_t)ng * 64 * 4);
    unsigned* bkt    = (unsigned*)H;   // alias: bkt (19.2 MB padded) dead before H's first write
    (void)ws_size; (void)n_in; (void)out_size;

    const int per_wg = 8192;
    const int nwg_e = cdiv(e, per_wg);

    // ---- one-time weight transpose + CSR build ----
    k_twist<<<cdiv(5120, BLK), BLK, 0, stream>>>(W2, W3, W4, Wt2, Wt3, Wt4);
    k_initcur<<<cdiv(nbk, BLK), BLK, 0, stream>>>(cursor, nbk);
    k_part<<<nwg_e, PBLK, 0, stream>>>(row, col, cursor, bkt, e, nbk, per_wg);
    k_bucket<<<nbk, BLK, 0, stream>>>(bkt, cursor, colstart, cntarr, srow, dinv, n);

    // ---- layer 1: 3 -> 16 (fused agg+tf) -> A0 ----
    k_scale3<<<cdiv((long)n * 3, BLK), BLK, 0, stream>>>(x, dinv, XS3, n);
    k_agg3tf<<<cdiv(n, BLK), BLK, 0, stream>>>(colstart, cntarr, srow, XS3, dinv, W1, b1, A0, n);

    // ---- layer 2: 16 -> 32 (fused; A0 is 3.2MB, L2-resident) -> B0,B1 ----
    k_aggtf2<<<cdiv(n, 32), 256, 0, stream>>>(colstart, cntarr, srow,
        (const __half2*)A0, dinv, Wt2, b2, B0, B1, n);

    // ---- layer 3: 32 -> 48 (2 chunked gather passes + transform) -> C0,C1,C2 ----
    k_agg16<<<cdiv((long)n * 4, 256), 256, 0, stream>>>(colstart, cntarr, srow, (const __half2*)B0, dinv, Y0, n);
    k_agg16<<<cdiv((long)n * 4, 256), 256, 0, stream>>>(colstart, cntarr, srow, (const __half2*)B1, dinv, Y1, n);
    k_tf32<<<cdiv((long)n * 12, 256), 256, 0, stream>>>((const __half2*)Y0, (const __half2*)Y1,
        Wt3, b3, dinv, C0, C1, C2, n);

    // ---- layer 4: 48 -> 64 (3 chunked gather passes + transform) -> H ----
    k_agg16<<<cdiv((long)n * 4, 256), 256, 0, stream>>>(colstart, cntarr, srow, (const __half2*)C0, dinv, Y0, n);
    k_agg16<<<cdiv((long)n * 4, 256), 256, 0, stream>>>(colstart, cntarr, srow, (const __half2*)C1, dinv, Y1, n);
    k_agg16<<<cdiv((long)n * 4, 256), 256, 0, stream>>>(colstart, cntarr, srow, (const __half2*)C2, dinv, Y2, n);
    k_tf48<<<cdiv((long)n * 16, 256), 256, 0, stream>>>((const __half2*)Y0, (const __half2*)Y1,
        (const __half2*)Y2, Wt4, b4, H, n);

    // ---- pool + MLP head ----
    k_gbound<<<cdiv(n, BLK), BLK, 0, stream>>>(batch, gstart, n);
    k_pool<<<ng, 256, 0, stream>>>(H, gstart, G);
    k_mlp1<<<cdiv(ng * 64, BLK), BLK, 0, stream>>>(G, L1w, L1b, G2, ng);
    k_mlp2<<<cdiv(ng * 10, BLK), BLK, 0, stream>>>(G2, L2w, L2b, out, ng);
}

// Round 12
// 277.038 us; speedup vs baseline: 1.1905x; 1.1905x over previous
//
#include <hip/hip_runtime.h>
#include <hip/hip_fp16.h>

#define BLK 256
#define PBLK 1024                // k_part block size
#define PER_WG 6400              // edges per k_part block (grid = 500, ~2/CU balanced)
#define BSHIFT 8                 // bucket span = 256 nodes
#define BSPAN 256
#define CAPSLOT 12288            // padded per-bucket slot (edges); mean ~8192, +45 sigma

static inline int cdiv(long a, int b) { return (int)((a + b - 1) / b); }

// cursor[b] = b * CAPSLOT
__global__ __launch_bounds__(BLK) void k_initcur(int* __restrict__ cursor, int nbk) {
    int i = blockIdx.x * BLK + threadIdx.x;
    if (i < nbk) cursor[i] = i * CAPSLOT;
}

// one-time weight transpose: Wt[k*Cout+co] = W[co*Cin+k] for layers 2,3,4
__global__ __launch_bounds__(BLK) void k_twist(const float* __restrict__ W2, const float* __restrict__ W3,
                                               const float* __restrict__ W4, float* __restrict__ Wt2,
                                               float* __restrict__ Wt3, float* __restrict__ Wt4) {
    int t = blockIdx.x * BLK + threadIdx.x;
    if (t < 512) {                       // 32x16
        int co = t % 32, k = t / 32;
        Wt2[k * 32 + co] = W2[co * 16 + k];
    } else if (t < 512 + 1536) {         // 48x32
        int u = t - 512; int co = u % 48, k = u / 48;
        Wt3[k * 48 + co] = W3[co * 32 + k];
    } else if (t < 512 + 1536 + 3072) {  // 64x48
        int u = t - 2048; int co = u % 64, k = u / 64;
        Wt4[k * 64 + co] = W4[co * 48 + k];
    }
}

// partition edges into padded coarse buckets; packed = (col & 255) << 17 | row   (row < 2^17)
// LDS-staged: scatter into per-bucket LDS runs, then bucket-major coalesced flush.
__global__ __launch_bounds__(PBLK) void k_part(const int* __restrict__ row, const int* __restrict__ col,
                                               int* __restrict__ cursor, unsigned* __restrict__ bkt,
                                               int e, int nbk) {
    __shared__ int h[512];
    __shared__ int base_l[512];
    __shared__ int pfx[512];          // inclusive scan of h
    __shared__ int c2[512];
    __shared__ unsigned staged[PER_WG];   // 25.6 KB
    int tid = threadIdx.x;
    for (int i = tid; i < 512; i += PBLK) h[i] = 0;
    __syncthreads();
    int base = blockIdx.x * PER_WG;
    int end = min(e, base + PER_WG);
    for (int i = base + tid; i < end; i += PBLK) atomicAdd(&h[col[i] >> BSHIFT], 1);
    __syncthreads();
    // reserve global runs + copy h into pfx for scan
    for (int i = tid; i < 512; i += PBLK) {
        base_l[i] = (i < nbk && h[i]) ? atomicAdd(&cursor[i], h[i]) : 0;
        pfx[i] = h[i];
        c2[i] = 0;
    }
    __syncthreads();
    // Hillis-Steele inclusive scan over 512
#pragma unroll
    for (int d = 1; d < 512; d <<= 1) {
        int v = 0;
        if (tid < 512) { v = pfx[tid]; if (tid >= d) v += pfx[tid - d]; }
        __syncthreads();
        if (tid < 512) pfx[tid] = v;
        __syncthreads();
    }
    // scatter into LDS runs (run start = pfx[b]-h[b])
    for (int i = base + tid; i < end; i += PBLK) {
        int c = col[i];
        int b = c >> BSHIFT;
        int slot = atomicAdd(&c2[b], 1);
        staged[pfx[b] - h[b] + slot] = ((unsigned)(c & (BSPAN - 1)) << 17) | (unsigned)row[i];
    }
    __syncthreads();
    // bucket-major flush: lanes write consecutive addresses within each run (coalesced)
    int wid = tid >> 6, lane = tid & 63;
    constexpr int NW = PBLK >> 6;
    for (int b = wid; b < nbk; b += NW) {
        int L = h[b];
        if (!L) continue;
        int g = base_l[b], p = pfx[b] - L;
        for (int k = lane; k < L; k += 64) bkt[g + k] = staged[p + k];
    }
}

// one WG per bucket: LDS counting sort -> coalesced srow (padded layout), colstart/cnt/dinv
__global__ __launch_bounds__(BLK) void k_bucket(const unsigned* __restrict__ bkt, const int* __restrict__ cursor,
                                                int* __restrict__ colstart, int* __restrict__ cntarr,
                                                int* __restrict__ srow, float* __restrict__ dinv, int n) {
    __shared__ int stage[CAPSLOT];   // 48 KB
    __shared__ int deg[BSPAN];
    __shared__ int pfx[BSPAN];
    int b = blockIdx.x;
    int eb = b * CAPSLOT;
    int ee = min(cursor[b], eb + CAPSLOT);
    int cnt = ee - eb;
    int n0 = b << BSHIFT;
    int nn = min(BSPAN, n - n0);
    for (int i = threadIdx.x; i < nn; i += BLK) deg[i] = 0;
    __syncthreads();
    for (int i = eb + threadIdx.x; i < ee; i += BLK) atomicAdd(&deg[bkt[i] >> 17], 1);
    __syncthreads();
    if (threadIdx.x == 0) {
        int acc = 0;
        for (int i = 0; i < nn; ++i) { pfx[i] = acc; acc += deg[i]; }
    }
    __syncthreads();
    for (int i = threadIdx.x; i < nn; i += BLK) {
        colstart[n0 + i] = eb + pfx[i];
        cntarr[n0 + i] = deg[i];
        dinv[n0 + i] = rsqrtf((float)(deg[i] + 1));   // +1 self-loop
    }
    __syncthreads();
    for (int i = eb + threadIdx.x; i < ee; i += BLK) {
        unsigned p = bkt[i];
        int s = atomicAdd(&pfx[p >> 17], 1);
        stage[s] = (int)(p & 0x1FFFFu);
    }
    __syncthreads();
    for (int i = threadIdx.x; i < cnt; i += BLK) srow[eb + i] = stage[i];  // coalesced
}

// xs3[i,c] = dinv[i] * x[i,c]
__global__ __launch_bounds__(BLK) void k_scale3(const float* __restrict__ x, const float* __restrict__ dinv,
                                                float* __restrict__ xs, int n) {
    int t = blockIdx.x * BLK + threadIdx.x;
    if (t >= n * 3) return;
    xs[t] = dinv[t / 3] * x[t];
}

// fused layer 1: 3-ch fp32 agg (thread per node) + 3->16 transform + fp16 prescaled output
__global__ __launch_bounds__(BLK) void k_agg3tf(const int* __restrict__ colstart, const int* __restrict__ cntarr,
                                                const int* __restrict__ srow, const float* __restrict__ xs3,
                                                const float* __restrict__ dinv, const float* __restrict__ W,
                                                const float* __restrict__ bias, __half* __restrict__ xs_out, int n) {
    __shared__ float sW[48];
    __shared__ float sB[16];
    if (threadIdx.x < 48) sW[threadIdx.x] = W[threadIdx.x];
    if (threadIdx.x < 16) sB[threadIdx.x] = bias[threadIdx.x];
    __syncthreads();
    int node = blockIdx.x * BLK + threadIdx.x;
    if (node >= n) return;
    float a0 = xs3[node * 3], a1 = xs3[node * 3 + 1], a2 = xs3[node * 3 + 2];
    int jb = colstart[node], je = jb + cntarr[node];
    int j = jb;
    for (; j + 1 < je; j += 2) {
        const float* p0 = xs3 + (size_t)srow[j] * 3;
        const float* p1 = xs3 + (size_t)srow[j + 1] * 3;
        a0 += p0[0] + p1[0]; a1 += p0[1] + p1[1]; a2 += p0[2] + p1[2];
    }
    if (j < je) {
        const float* p = xs3 + (size_t)srow[j] * 3;
        a0 += p[0]; a1 += p[1]; a2 += p[2];
    }
    float d = dinv[node];
    float y0 = d * a0, y1 = d * a1, y2 = d * a2;
#pragma unroll
    for (int q = 0; q < 4; ++q) {
        float v[4];
#pragma unroll
        for (int jj = 0; jj < 4; ++jj) {
            int co = q * 4 + jj;
            float acc = sB[co] + y0 * sW[co * 3] + y1 * sW[co * 3 + 1] + y2 * sW[co * 3 + 2];
            v[jj] = d * fmaxf(acc, 0.0f);
        }
        __half2 h0 = __halves2half2(__float2half(v[0]), __float2half(v[1]));
        __half2 h1 = __halves2half2(__float2half(v[2]), __float2half(v[3]));
        uint2 u = make_uint2(*(unsigned*)&h0, *(unsigned*)&h1);
        ((uint2*)xs_out)[(size_t)node * 4 + q] = u;
    }
}

// fused mid/last layer: fp16 gather-agg (LPN lanes/node) -> LDS y -> transform
// Wt is PRE-TRANSPOSED [Cin][Cout] (coalesced, conflict-free staging).
// HALFOUT: write dinv*relu as fp16 (pre-scaled for next gather); else fp32 relu (H for pool).
template<int C, int LPN, int Cout, bool HALFOUT>
__global__ __launch_bounds__(256) void k_aggtf(const int* __restrict__ colstart, const int* __restrict__ cntarr,
                                               const int* __restrict__ srow, const __half2* __restrict__ xs,
                                               const float* __restrict__ dinv, const float* __restrict__ Wt,
                                               const float* __restrict__ bias, void* __restrict__ outp, int n) {
    constexpr int TPB = 256;
    constexpr int HC = C / 2;
    constexpr int H2PL = HC / LPN;      // half2 per lane
    constexpr int NPB = TPB / LPN;      // nodes per block (32)
    constexpr int QPN = Cout / 4;
    constexpr int CP = C + 4;           // padded LDS row (bank rotation)
    __shared__ __align__(16) float yb[NPB][CP];
    __shared__ __align__(16) float smWt[C * Cout];
    __shared__ __align__(16) float smB[Cout];
    for (int idx = threadIdx.x; idx < C * Cout; idx += TPB) smWt[idx] = Wt[idx];  // coalesced copy
    if (threadIdx.x < Cout) smB[threadIdx.x] = bias[threadIdx.x];

    // ---- phase 1: aggregate into LDS ----
    int nl = threadIdx.x / LPN;
    int c0 = threadIdx.x % LPN;
    int node = blockIdx.x * NPB + nl;
    if (node < n) {
        float2 acc[H2PL];
        const __half2* self = xs + (size_t)node * HC + c0 * H2PL;
#pragma unroll
        for (int h = 0; h < H2PL; ++h) acc[h] = __half22float2(self[h]);
        int jb = colstart[node], je = jb + cntarr[node];
        int j = jb;
        for (; j + 3 < je; j += 4) {
            int r0 = srow[j], r1 = srow[j + 1], r2 = srow[j + 2], r3 = srow[j + 3];
            const __half2* p0 = xs + (size_t)r0 * HC + c0 * H2PL;
            const __half2* p1 = xs + (size_t)r1 * HC + c0 * H2PL;
            const __half2* p2 = xs + (size_t)r2 * HC + c0 * H2PL;
            const __half2* p3 = xs + (size_t)r3 * HC + c0 * H2PL;
#pragma unroll
            for (int h = 0; h < H2PL; ++h) {
                float2 f0 = __half22float2(p0[h]), f1 = __half22float2(p1[h]);
                float2 f2 = __half22float2(p2[h]), f3 = __half22float2(p3[h]);
                acc[h].x += (f0.x + f1.x) + (f2.x + f3.x);
                acc[h].y += (f0.y + f1.y) + (f2.y + f3.y);
            }
        }
        for (; j < je; ++j) {
            const __half2* p = xs + (size_t)srow[j] * HC + c0 * H2PL;
#pragma unroll
            for (int h = 0; h < H2PL; ++h) {
                float2 f = __half22float2(p[h]);
                acc[h].x += f.x; acc[h].y += f.y;
            }
        }
        float d = dinv[node];
#pragma unroll
        for (int h = 0; h < H2PL; ++h) {
            *(float2*)&yb[nl][(c0 * H2PL + h) * 2] = make_float2(d * acc[h].x, d * acc[h].y);
        }
    }
    __syncthreads();

    // ---- phase 2: transform from LDS ----
    int base = blockIdx.x * NPB;
    for (int idx = threadIdx.x; idx < NPB * QPN; idx += TPB) {
        int nl2 = idx / QPN, q = idx % QPN;
        int nd = base + nl2;
        if (nd >= n) break;   // nd nondecreasing in idx
        const float* yr = yb[nl2];
        float4 bb = ((const float4*)smB)[q];
        float a0 = bb.x, a1 = bb.y, a2 = bb.z, a3 = bb.w;
        const float4* wt = (const float4*)smWt;
#pragma unroll
        for (int k = 0; k < C; ++k) {
            float yk = yr[k];
            float4 w = wt[k * QPN + q];
            a0 = fmaf(yk, w.x, a0); a1 = fmaf(yk, w.y, a1);
            a2 = fmaf(yk, w.z, a2); a3 = fmaf(yk, w.w, a3);
        }
        a0 = fmaxf(a0, 0.f); a1 = fmaxf(a1, 0.f); a2 = fmaxf(a2, 0.f); a3 = fmaxf(a3, 0.f);
        if constexpr (HALFOUT) {
            float d = dinv[nd];
            __half2 h0 = __halves2half2(__float2half(d * a0), __float2half(d * a1));
            __half2 h1 = __halves2half2(__float2half(d * a2), __float2half(d * a3));
            uint2 u = make_uint2(*(unsigned*)&h0, *(unsigned*)&h1);
            ((uint2*)outp)[(size_t)nd * QPN + q] = u;
        } else {
            ((float4*)outp)[(size_t)nd * QPN + q] = make_float4(a0, a1, a2, a3);
        }
    }
}

// batch is sorted -> graph boundaries
__global__ __launch_bounds__(BLK) void k_gbound(const int* __restrict__ batch, int* __restrict__ gstart, int n) {
    int i = blockIdx.x * BLK + threadIdx.x;
    if (i >= n) return;
    int b = batch[i];
    int pb = (i == 0) ? -1 : batch[i - 1];
    for (int g = pb + 1; g <= b; ++g) gstart[g] = i;
    if (i == n - 1) {
        for (int g = b + 1; g <= 256; ++g) gstart[g] = n;
    }
}

__global__ __launch_bounds__(256) void k_pool(const float* __restrict__ h, const int* __restrict__ gstart,
                                              float* __restrict__ g) {
    int gr = blockIdx.x;
    int c = threadIdx.x & 63, s = threadIdx.x >> 6;
    int i0 = gstart[gr], i1 = gstart[gr + 1];
    float m = 0.0f;
    for (int i = i0 + s; i < i1; i += 4) m = fmaxf(m, h[(size_t)i * 64 + c]);
    __shared__ float sm[256];
    sm[threadIdx.x] = m;
    __syncthreads();
    if (s == 0) {
        m = fmaxf(fmaxf(sm[c], sm[64 + c]), fmaxf(sm[128 + c], sm[192 + c]));
        g[gr * 64 + c] = m;
    }
}

__global__ __launch_bounds__(BLK) void k_mlp1(const float* __restrict__ g, const float* __restrict__ W,
                                              const float* __restrict__ b, float* __restrict__ g2, int ng) {
    int t = blockIdx.x * BLK + threadIdx.x;
    if (t >= ng * 64) return;
    int gi = t >> 6, co = t & 63;
    const float* gv = g + (gi << 6);
    const float* ws = W + co * 64;
    float acc = b[co];
#pragma unroll
    for (int k = 0; k < 64; ++k) acc = fmaf(gv[k], ws[k], acc);
    g2[t] = fmaxf(acc, 0.0f);
}

__global__ __launch_bounds__(BLK) void k_mlp2(const float* __restrict__ g2, const float* __restrict__ W,
                                              const float* __restrict__ b, float* __restrict__ out, int ng) {
    int t = blockIdx.x * BLK + threadIdx.x;
    if (t >= ng * 10) return;
    int gi = t / 10, co = t % 10;
    const float* gv = g2 + (gi << 6);
    const float* ws = W + co * 64;
    float acc = b[co];
#pragma unroll
    for (int k = 0; k < 64; ++k) acc = fmaf(gv[k], ws[k], acc);
    out[t] = acc;
}

extern "C" void kernel_launch(void* const* d_in, const int* in_sizes, int n_in,
                              void* d_out, int out_size, void* d_ws, size_t ws_size,
                              hipStream_t stream) {
    const float* x     = (const float*)d_in[0];
    const int*   ei    = (const int*)d_in[1];
    const int*   batch = (const int*)d_in[2];
    const float *W1 = (const float*)d_in[4],  *b1 = (const float*)d_in[5];
    const float *W2 = (const float*)d_in[6],  *b2 = (const float*)d_in[7];
    const float *W3 = (const float*)d_in[8],  *b3 = (const float*)d_in[9];
    const float *W4 = (const float*)d_in[10], *b4 = (const float*)d_in[11];
    const float *L1w = (const float*)d_in[12], *L1b = (const float*)d_in[13];
    const float *L2w = (const float*)d_in[14], *L2b = (const float*)d_in[15];
    float* out = (float*)d_out;

    const int n  = in_sizes[0] / 3;   // 100000 (row ids fit 17 bits)
    const int e  = in_sizes[1] / 2;   // 3200000
    const int ng = 256;
    const int* row = ei;
    const int* col = ei + e;
    const int nbk = cdiv(n, BSPAN);   // 391 coarse buckets

    char* ws = (char*)d_ws;
    size_t off = 0;
    auto alloc = [&](size_t bytes) -> void* {
        void* p = ws + off;
        off += (bytes + 255) & ~(size_t)255;
        return p;
    };
    int*    colstart = (int*)alloc((size_t)n * 4);
    int*    cntarr   = (int*)alloc((size_t)n * 4);
    float*  dinv     = (float*)alloc((size_t)n * 4);
    int*    srow     = (int*)alloc((size_t)nbk * CAPSLOT * 4);   // 19.2 MB padded
    int*    cursor   = (int*)alloc(512 * 4);
    int*    gstart   = (int*)alloc(257 * 4);
    float*  Wt2      = (float*)alloc(512 * 4);
    float*  Wt3      = (float*)alloc(1536 * 4);
    float*  Wt4      = (float*)alloc(3072 * 4);
    float*  XS3      = (float*)alloc((size_t)n * 3 * 4);
    __half* XSA      = (__half*)alloc((size_t)n * 48 * 2);       // ping
    __half* XSB      = (__half*)alloc((size_t)n * 48 * 2);       // pong
    float*  H        = (float*)alloc((size_t)n * 64 * 4);
    float*  G        = (float*)alloc((size_t)ng * 64 * 4);
    float*  G2       = (float*)alloc((size_t)ng * 64 * 4);
    unsigned* bkt    = (unsigned*)H;   // alias: bkt (12.8 MB) dead before H's first write
    (void)ws_size; (void)n_in; (void)out_size;

    // ---- one-time weight transpose + CSR build ----
    k_twist<<<cdiv(5120, BLK), BLK, 0, stream>>>(W2, W3, W4, Wt2, Wt3, Wt4);
    k_initcur<<<cdiv(nbk, BLK), BLK, 0, stream>>>(cursor, nbk);
    k_part<<<cdiv(e, PER_WG), PBLK, 0, stream>>>(row, col, cursor, bkt, e, nbk);
    k_bucket<<<nbk, BLK, 0, stream>>>(bkt, cursor, colstart, cntarr, srow, dinv, n);

    // ---- layer 1: 3 -> 16 (fused agg+tf) ----
    k_scale3<<<cdiv((long)n * 3, BLK), BLK, 0, stream>>>(x, dinv, XS3, n);
    k_agg3tf<<<cdiv(n, BLK), BLK, 0, stream>>>(colstart, cntarr, srow, XS3, dinv, W1, b1, XSA, n);

    // ---- layer 2: 16 -> 32 (fused, XSA -> XSB) ----
    k_aggtf<16, 8, 32, true><<<cdiv(n, 32), 256, 0, stream>>>(colstart, cntarr, srow,
        (const __half2*)XSA, dinv, Wt2, b2, XSB, n);

    // ---- layer 3: 32 -> 48 (fused, XSB -> XSA) ----
    k_aggtf<32, 8, 48, true><<<cdiv(n, 32), 256, 0, stream>>>(colstart, cntarr, srow,
        (const __half2*)XSB, dinv, Wt3, b3, XSA, n);

    // ---- layer 4: 48 -> 64 (fused, XSA -> H) ----
    k_aggtf<48, 8, 64, false><<<cdiv(n, 32), 256, 0, stream>>>(colstart, cntarr, srow,
        (const __half2*)XSA, dinv, Wt4, b4, H, n);

    // ---- pool + MLP head ----
    k_gbound<<<cdiv(n, BLK), BLK, 0, stream>>>(batch, gstart, n);
    k_pool<<<ng, 256, 0, stream>>>(H, gstart, G);
    k_mlp1<<<cdiv(ng * 64, BLK), BLK, 0, stream>>>(G, L1w, L1b, G2, ng);
    k_mlp2<<<cdiv(ng * 10, BLK), BLK, 0, stream>>>(G2, L2w, L2b, out, ng);
}

// Round 13
// 256.814 us; speedup vs baseline: 1.2843x; 1.0787x over previous
//
#include <hip/hip_runtime.h>
#include <hip/hip_fp16.h>

#define BLK 256
#define PBLK 1024                // k_part block size
#define PER_WG 6400              // edges per k_part block (grid = 500, ~2/CU balanced)
#define BSHIFT 8                 // bucket span = 256 nodes
#define BSPAN 256
#define CAPSLOT 12288            // padded per-bucket slot (edges); mean ~8192, +45 sigma

static inline int cdiv(long a, int b) { return (int)((a + b - 1) / b); }

// cursor[b] = b * CAPSLOT
__global__ __launch_bounds__(BLK) void k_initcur(int* __restrict__ cursor, int nbk) {
    int i = blockIdx.x * BLK + threadIdx.x;
    if (i < nbk) cursor[i] = i * CAPSLOT;
}

// one-time weight transpose: Wt[k*Cout+co] = W[co*Cin+k] for layers 2,3,4
__global__ __launch_bounds__(BLK) void k_twist(const float* __restrict__ W2, const float* __restrict__ W3,
                                               const float* __restrict__ W4, float* __restrict__ Wt2,
                                               float* __restrict__ Wt3, float* __restrict__ Wt4) {
    int t = blockIdx.x * BLK + threadIdx.x;
    if (t < 512) {                       // 32x16
        int co = t % 32, k = t / 32;
        Wt2[k * 32 + co] = W2[co * 16 + k];
    } else if (t < 512 + 1536) {         // 48x32
        int u = t - 512; int co = u % 48, k = u / 48;
        Wt3[k * 48 + co] = W3[co * 32 + k];
    } else if (t < 512 + 1536 + 3072) {  // 64x48
        int u = t - 2048; int co = u % 64, k = u / 64;
        Wt4[k * 64 + co] = W4[co * 48 + k];
    }
}

// partition edges into padded coarse buckets; packed = (col & 255) << 17 | row   (row < 2^17)
// LDS-staged: scatter into per-bucket LDS runs, then bucket-major coalesced flush.
__global__ __launch_bounds__(PBLK) void k_part(const int* __restrict__ row, const int* __restrict__ col,
                                               int* __restrict__ cursor, unsigned* __restrict__ bkt,
                                               int e, int nbk) {
    __shared__ int h[512];
    __shared__ int base_l[512];
    __shared__ int pfx[512];          // inclusive scan of h
    __shared__ int c2[512];
    __shared__ unsigned staged[PER_WG];   // 25.6 KB
    int tid = threadIdx.x;
    for (int i = tid; i < 512; i += PBLK) h[i] = 0;
    __syncthreads();
    int base = blockIdx.x * PER_WG;
    int end = min(e, base + PER_WG);
    for (int i = base + tid; i < end; i += PBLK) atomicAdd(&h[col[i] >> BSHIFT], 1);
    __syncthreads();
    for (int i = tid; i < 512; i += PBLK) {
        base_l[i] = (i < nbk && h[i]) ? atomicAdd(&cursor[i], h[i]) : 0;
        pfx[i] = h[i];
        c2[i] = 0;
    }
    __syncthreads();
#pragma unroll
    for (int d = 1; d < 512; d <<= 1) {
        int v = 0;
        if (tid < 512) { v = pfx[tid]; if (tid >= d) v += pfx[tid - d]; }
        __syncthreads();
        if (tid < 512) pfx[tid] = v;
        __syncthreads();
    }
    for (int i = base + tid; i < end; i += PBLK) {
        int c = col[i];
        int b = c >> BSHIFT;
        int slot = atomicAdd(&c2[b], 1);
        staged[pfx[b] - h[b] + slot] = ((unsigned)(c & (BSPAN - 1)) << 17) | (unsigned)row[i];
    }
    __syncthreads();
    int wid = tid >> 6, lane = tid & 63;
    constexpr int NW = PBLK >> 6;
    for (int b = wid; b < nbk; b += NW) {
        int L = h[b];
        if (!L) continue;
        int g = base_l[b], p = pfx[b] - L;
        for (int k = lane; k < L; k += 64) bkt[g + k] = staged[p + k];
    }
}

// one WG per bucket: LDS counting sort -> coalesced srow (padded layout), colstart/cnt/dinv
__global__ __launch_bounds__(BLK) void k_bucket(const unsigned* __restrict__ bkt, const int* __restrict__ cursor,
                                                int* __restrict__ colstart, int* __restrict__ cntarr,
                                                int* __restrict__ srow, float* __restrict__ dinv, int n) {
    __shared__ int stage[CAPSLOT];   // 48 KB
    __shared__ int deg[BSPAN];
    __shared__ int pfx[BSPAN];
    int b = blockIdx.x;
    int eb = b * CAPSLOT;
    int ee = min(cursor[b], eb + CAPSLOT);
    int cnt = ee - eb;
    int n0 = b << BSHIFT;
    int nn = min(BSPAN, n - n0);
    for (int i = threadIdx.x; i < nn; i += BLK) deg[i] = 0;
    __syncthreads();
    for (int i = eb + threadIdx.x; i < ee; i += BLK) atomicAdd(&deg[bkt[i] >> 17], 1);
    __syncthreads();
    if (threadIdx.x == 0) {
        int acc = 0;
        for (int i = 0; i < nn; ++i) { pfx[i] = acc; acc += deg[i]; }
    }
    __syncthreads();
    for (int i = threadIdx.x; i < nn; i += BLK) {
        colstart[n0 + i] = eb + pfx[i];
        cntarr[n0 + i] = deg[i];
        dinv[n0 + i] = rsqrtf((float)(deg[i] + 1));   // +1 self-loop
    }
    __syncthreads();
    for (int i = eb + threadIdx.x; i < ee; i += BLK) {
        unsigned p = bkt[i];
        int s = atomicAdd(&pfx[p >> 17], 1);
        stage[s] = (int)(p & 0x1FFFFu);
    }
    __syncthreads();
    for (int i = threadIdx.x; i < cnt; i += BLK) srow[eb + i] = stage[i];  // coalesced
}

// xs3h[i] = {dinv*x0, dinv*x1, dinv*x2, 0} as 4 halves (8B aligned)
__global__ __launch_bounds__(BLK) void k_scale3h(const float* __restrict__ x, const float* __restrict__ dinv,
                                                 __half* __restrict__ xs3h, int n) {
    int i = blockIdx.x * BLK + threadIdx.x;
    if (i >= n) return;
    float d = dinv[i];
    __half2 h0 = __halves2half2(__float2half(d * x[i * 3]), __float2half(d * x[i * 3 + 1]));
    __half2 h1 = __halves2half2(__float2half(d * x[i * 3 + 2]), __float2half(0.0f));
    ((uint2*)xs3h)[i] = make_uint2(*(unsigned*)&h0, *(unsigned*)&h1);
}

// fused layer 1: 3-ch fp16 agg (thread per node, 8B/edge) + 3->16 transform + fp16 prescaled output
__global__ __launch_bounds__(BLK) void k_agg3tf(const int* __restrict__ colstart, const int* __restrict__ cntarr,
                                                const int* __restrict__ srow, const uint2* __restrict__ xs3h,
                                                const float* __restrict__ dinv, const float* __restrict__ W,
                                                const float* __restrict__ bias, __half* __restrict__ xs_out, int n) {
    __shared__ float sW[48];
    __shared__ float sB[16];
    if (threadIdx.x < 48) sW[threadIdx.x] = W[threadIdx.x];
    if (threadIdx.x < 16) sB[threadIdx.x] = bias[threadIdx.x];
    __syncthreads();
    int node = blockIdx.x * BLK + threadIdx.x;
    if (node >= n) return;
    uint2 sv = xs3h[node];
    float2 s0 = __half22float2(*(__half2*)&sv.x);
    float2 s1 = __half22float2(*(__half2*)&sv.y);
    float a0 = s0.x, a1 = s0.y, a2 = s1.x;
    int jb = colstart[node], je = jb + cntarr[node];
    int j = jb;
    for (; j + 3 < je; j += 4) {
        int r0 = srow[j], r1 = srow[j + 1], r2 = srow[j + 2], r3 = srow[j + 3];
        uint2 v0 = xs3h[r0], v1 = xs3h[r1], v2 = xs3h[r2], v3 = xs3h[r3];
        float2 u0 = __half22float2(*(__half2*)&v0.x), u1 = __half22float2(*(__half2*)&v0.y);
        float2 w0 = __half22float2(*(__half2*)&v1.x), w1 = __half22float2(*(__half2*)&v1.y);
        float2 y0f = __half22float2(*(__half2*)&v2.x), y1f = __half22float2(*(__half2*)&v2.y);
        float2 z0 = __half22float2(*(__half2*)&v3.x), z1 = __half22float2(*(__half2*)&v3.y);
        a0 += (u0.x + w0.x) + (y0f.x + z0.x);
        a1 += (u0.y + w0.y) + (y0f.y + z0.y);
        a2 += (u1.x + w1.x) + (y1f.x + z1.x);
    }
    for (; j < je; ++j) {
        uint2 v = xs3h[srow[j]];
        float2 u0 = __half22float2(*(__half2*)&v.x), u1 = __half22float2(*(__half2*)&v.y);
        a0 += u0.x; a1 += u0.y; a2 += u1.x;
    }
    float d = dinv[node];
    float y0 = d * a0, y1 = d * a1, y2 = d * a2;
#pragma unroll
    for (int q = 0; q < 4; ++q) {
        float v[4];
#pragma unroll
        for (int jj = 0; jj < 4; ++jj) {
            int co = q * 4 + jj;
            float acc = sB[co] + y0 * sW[co * 3] + y1 * sW[co * 3 + 1] + y2 * sW[co * 3 + 2];
            v[jj] = d * fmaxf(acc, 0.0f);
        }
        __half2 h0 = __halves2half2(__float2half(v[0]), __float2half(v[1]));
        __half2 h1 = __halves2half2(__float2half(v[2]), __float2half(v[3]));
        uint2 u = make_uint2(*(unsigned*)&h0, *(unsigned*)&h1);
        ((uint2*)xs_out)[(size_t)node * 4 + q] = u;
    }
}

// fused mid/last layer: fp16 gather-agg (LPN lanes/node, 8-edge unroll) -> LDS y -> transform
// Wt is PRE-TRANSPOSED [Cin][Cout]. OMODE: 0 = fp32 out, 1 = fp16 prescaled (dinv*relu), 2 = fp16 relu.
template<int C, int LPN, int Cout, int OMODE>
__global__ __launch_bounds__(256) void k_aggtf(const int* __restrict__ colstart, const int* __restrict__ cntarr,
                                               const int* __restrict__ srow, const __half2* __restrict__ xs,
                                               const float* __restrict__ dinv, const float* __restrict__ Wt,
                                               const float* __restrict__ bias, void* __restrict__ outp, int n) {
    constexpr int TPB = 256;
    constexpr int HC = C / 2;
    constexpr int H2PL = HC / LPN;      // half2 per lane
    constexpr int NPB = TPB / LPN;      // nodes per block (32)
    constexpr int QPN = Cout / 4;
    constexpr int CP = C + 4;           // padded LDS row (bank rotation)
    __shared__ __align__(16) float yb[NPB][CP];
    __shared__ __align__(16) float smWt[C * Cout];
    __shared__ __align__(16) float smB[Cout];
    for (int idx = threadIdx.x; idx < C * Cout; idx += TPB) smWt[idx] = Wt[idx];  // coalesced copy
    if (threadIdx.x < Cout) smB[threadIdx.x] = bias[threadIdx.x];

    // ---- phase 1: aggregate into LDS ----
    int nl = threadIdx.x / LPN;
    int c0 = threadIdx.x % LPN;
    int node = blockIdx.x * NPB + nl;
    if (node < n) {
        float2 acc[H2PL];
        const __half2* self = xs + (size_t)node * HC + c0 * H2PL;
#pragma unroll
        for (int h = 0; h < H2PL; ++h) acc[h] = __half22float2(self[h]);
        int jb = colstart[node], je = jb + cntarr[node];
        int j = jb;
        for (; j + 7 < je; j += 8) {    // 8-edge unroll: ~24 loads in flight per lane
            int r[8];
#pragma unroll
            for (int u = 0; u < 8; ++u) r[u] = srow[j + u];
#pragma unroll
            for (int u = 0; u < 8; ++u) {
                const __half2* p = xs + (size_t)r[u] * HC + c0 * H2PL;
#pragma unroll
                for (int h = 0; h < H2PL; ++h) {
                    float2 f = __half22float2(p[h]);
                    acc[h].x += f.x; acc[h].y += f.y;
                }
            }
        }
        for (; j < je; ++j) {
            const __half2* p = xs + (size_t)srow[j] * HC + c0 * H2PL;
#pragma unroll
            for (int h = 0; h < H2PL; ++h) {
                float2 f = __half22float2(p[h]);
                acc[h].x += f.x; acc[h].y += f.y;
            }
        }
        float d = dinv[node];
#pragma unroll
        for (int h = 0; h < H2PL; ++h) {
            *(float2*)&yb[nl][(c0 * H2PL + h) * 2] = make_float2(d * acc[h].x, d * acc[h].y);
        }
    }
    __syncthreads();

    // ---- phase 2: transform from LDS ----
    int base = blockIdx.x * NPB;
    for (int idx = threadIdx.x; idx < NPB * QPN; idx += TPB) {
        int nl2 = idx / QPN, q = idx % QPN;
        int nd = base + nl2;
        if (nd >= n) break;   // nd nondecreasing in idx
        const float* yr = yb[nl2];
        float4 bb = ((const float4*)smB)[q];
        float a0 = bb.x, a1 = bb.y, a2 = bb.z, a3 = bb.w;
        const float4* wt = (const float4*)smWt;
#pragma unroll
        for (int k = 0; k < C; ++k) {
            float yk = yr[k];
            float4 w = wt[k * QPN + q];
            a0 = fmaf(yk, w.x, a0); a1 = fmaf(yk, w.y, a1);
            a2 = fmaf(yk, w.z, a2); a3 = fmaf(yk, w.w, a3);
        }
        a0 = fmaxf(a0, 0.f); a1 = fmaxf(a1, 0.f); a2 = fmaxf(a2, 0.f); a3 = fmaxf(a3, 0.f);
        if constexpr (OMODE == 0) {
            ((float4*)outp)[(size_t)nd * QPN + q] = make_float4(a0, a1, a2, a3);
        } else {
            if constexpr (OMODE == 1) {
                float d = dinv[nd];
                a0 *= d; a1 *= d; a2 *= d; a3 *= d;
            }
            __half2 h0 = __halves2half2(__float2half(a0), __float2half(a1));
            __half2 h1 = __halves2half2(__float2half(a2), __float2half(a3));
            uint2 u = make_uint2(*(unsigned*)&h0, *(unsigned*)&h1);
            ((uint2*)outp)[(size_t)nd * QPN + q] = u;
        }
    }
}

// batch is sorted -> graph boundaries
__global__ __launch_bounds__(BLK) void k_gbound(const int* __restrict__ batch, int* __restrict__ gstart, int n) {
    int i = blockIdx.x * BLK + threadIdx.x;
    if (i >= n) return;
    int b = batch[i];
    int pb = (i == 0) ? -1 : batch[i - 1];
    for (int g = pb + 1; g <= b; ++g) gstart[g] = i;
    if (i == n - 1) {
        for (int g = b + 1; g <= 256; ++g) gstart[g] = n;
    }
}

// pool over fp16 H (values >= 0)
__global__ __launch_bounds__(256) void k_pool(const __half* __restrict__ h, const int* __restrict__ gstart,
                                              float* __restrict__ g) {
    int gr = blockIdx.x;
    int c = threadIdx.x & 63, s = threadIdx.x >> 6;
    int i0 = gstart[gr], i1 = gstart[gr + 1];
    float m = 0.0f;
    for (int i = i0 + s; i < i1; i += 4) m = fmaxf(m, __half2float(h[(size_t)i * 64 + c]));
    __shared__ float sm[256];
    sm[threadIdx.x] = m;
    __syncthreads();
    if (s == 0) {
        m = fmaxf(fmaxf(sm[c], sm[64 + c]), fmaxf(sm[128 + c], sm[192 + c]));
        g[gr * 64 + c] = m;
    }
}

__global__ __launch_bounds__(BLK) void k_mlp1(const float* __restrict__ g, const float* __restrict__ W,
                                              const float* __restrict__ b, float* __restrict__ g2, int ng) {
    int t = blockIdx.x * BLK + threadIdx.x;
    if (t >= ng * 64) return;
    int gi = t >> 6, co = t & 63;
    const float* gv = g + (gi << 6);
    const float* ws = W + co * 64;
    float acc = b[co];
#pragma unroll
    for (int k = 0; k < 64; ++k) acc = fmaf(gv[k], ws[k], acc);
    g2[t] = fmaxf(acc, 0.0f);
}

__global__ __launch_bounds__(BLK) void k_mlp2(const float* __restrict__ g2, const float* __restrict__ W,
                                              const float* __restrict__ b, float* __restrict__ out, int ng) {
    int t = blockIdx.x * BLK + threadIdx.x;
    if (t >= ng * 10) return;
    int gi = t / 10, co = t % 10;
    const float* gv = g2 + (gi << 6);
    const float* ws = W + co * 64;
    float acc = b[co];
#pragma unroll
    for (int k = 0; k < 64; ++k) acc = fmaf(gv[k], ws[k], acc);
    out[t] = acc;
}

extern "C" void kernel_launch(void* const* d_in, const int* in_sizes, int n_in,
                              void* d_out, int out_size, void* d_ws, size_t ws_size,
                              hipStream_t stream) {
    const float* x     = (const float*)d_in[0];
    const int*   ei    = (const int*)d_in[1];
    const int*   batch = (const int*)d_in[2];
    const float *W1 = (const float*)d_in[4],  *b1 = (const float*)d_in[5];
    const float *W2 = (const float*)d_in[6],  *b2 = (const float*)d_in[7];
    const float *W3 = (const float*)d_in[8],  *b3 = (const float*)d_in[9];
    const float *W4 = (const float*)d_in[10], *b4 = (const float*)d_in[11];
    const float *L1w = (const float*)d_in[12], *L1b = (const float*)d_in[13];
    const float *L2w = (const float*)d_in[14], *L2b = (const float*)d_in[15];
    float* out = (float*)d_out;

    const int n  = in_sizes[0] / 3;   // 100000 (row ids fit 17 bits)
    const int e  = in_sizes[1] / 2;   // 3200000
    const int ng = 256;
    const int* row = ei;
    const int* col = ei + e;
    const int nbk = cdiv(n, BSPAN);   // 391 coarse buckets

    char* ws = (char*)d_ws;
    size_t off = 0;
    auto alloc = [&](size_t bytes) -> void* {
        void* p = ws + off;
        off += (bytes + 255) & ~(size_t)255;
        return p;
    };
    int*    colstart = (int*)alloc((size_t)n * 4);
    int*    cntarr   = (int*)alloc((size_t)n * 4);
    float*  dinv     = (float*)alloc((size_t)n * 4);
    int*    srow     = (int*)alloc((size_t)nbk * CAPSLOT * 4);   // 19.2 MB padded
    int*    cursor   = (int*)alloc(512 * 4);
    int*    gstart   = (int*)alloc(257 * 4);
    float*  Wt2      = (float*)alloc(512 * 4);
    float*  Wt3      = (float*)alloc(1536 * 4);
    float*  Wt4      = (float*)alloc(3072 * 4);
    __half* XS3H     = (__half*)alloc((size_t)n * 4 * 2);        // padded 4-half rows
    __half* XSA      = (__half*)alloc((size_t)n * 48 * 2);       // ping
    __half* XSB      = (__half*)alloc((size_t)n * 48 * 2);       // pong
    __half* H        = (__half*)alloc((size_t)n * 64 * 2);       // fp16 features for pool
    float*  G        = (float*)alloc((size_t)ng * 64 * 4);
    float*  G2       = (float*)alloc((size_t)ng * 64 * 4);
    unsigned* bkt    = (unsigned*)alloc((size_t)e * 4);          // 12.8 MB (no alias; ws is large)
    (void)ws_size; (void)n_in; (void)out_size;

    // ---- one-time weight transpose + CSR build ----
    k_twist<<<cdiv(5120, BLK), BLK, 0, stream>>>(W2, W3, W4, Wt2, Wt3, Wt4);
    k_initcur<<<cdiv(nbk, BLK), BLK, 0, stream>>>(cursor, nbk);
    k_part<<<cdiv(e, PER_WG), PBLK, 0, stream>>>(row, col, cursor, bkt, e, nbk);
    k_bucket<<<nbk, BLK, 0, stream>>>(bkt, cursor, colstart, cntarr, srow, dinv, n);

    // ---- layer 1: 3 -> 16 (fp16 8B/edge gather, fused) ----
    k_scale3h<<<cdiv(n, BLK), BLK, 0, stream>>>(x, dinv, XS3H, n);
    k_agg3tf<<<cdiv(n, BLK), BLK, 0, stream>>>(colstart, cntarr, srow, (const uint2*)XS3H, dinv, W1, b1, XSA, n);

    // ---- layer 2: 16 -> 32 (fused, XSA -> XSB) ----
    k_aggtf<16, 8, 32, 1><<<cdiv(n, 32), 256, 0, stream>>>(colstart, cntarr, srow,
        (const __half2*)XSA, dinv, Wt2, b2, XSB, n);

    // ---- layer 3: 32 -> 48 (fused, XSB -> XSA) ----
    k_aggtf<32, 8, 48, 1><<<cdiv(n, 32), 256, 0, stream>>>(colstart, cntarr, srow,
        (const __half2*)XSB, dinv, Wt3, b3, XSA, n);

    // ---- layer 4: 48 -> 64 (fused, XSA -> fp16 H) ----
    k_aggtf<48, 8, 64, 2><<<cdiv(n, 32), 256, 0, stream>>>(colstart, cntarr, srow,
        (const __half2*)XSA, dinv, Wt4, b4, H, n);

    // ---- pool + MLP head ----
    k_gbound<<<cdiv(n, BLK), BLK, 0, stream>>>(batch, gstart, n);
    k_pool<<<ng, 256, 0, stream>>>(H, gstart, G);
    k_mlp1<<<cdiv(ng * 64, BLK), BLK, 0, stream>>>(G, L1w, L1b, G2, ng);
    k_mlp2<<<cdiv(ng * 10, BLK), BLK, 0, stream>>>(G2, L2w, L2b, out, ng);
}

// Round 14
// 252.529 us; speedup vs baseline: 1.3061x; 1.0170x over previous
//
#include <hip/hip_runtime.h>
#include <hip/hip_fp16.h>

#define BLK 256
#define PBLK 1024                // k_part block size
#define PER_WG 6400              // edges per k_part block (grid = 500, ~2/CU balanced)
#define BSHIFT 8                 // bucket span = 256 nodes
#define BSPAN 256
#define CAPSLOT 12288            // padded per-bucket slot (edges); mean ~8192, +45 sigma

static inline int cdiv(long a, int b) { return (int)((a + b - 1) / b); }

// cursor[b] = b * CAPSLOT
__global__ __launch_bounds__(BLK) void k_initcur(int* __restrict__ cursor, int nbk) {
    int i = blockIdx.x * BLK + threadIdx.x;
    if (i < nbk) cursor[i] = i * CAPSLOT;
}

// one-time weight transpose: Wt[k*Cout+co] = W[co*Cin+k] for layers 2,3,4
__global__ __launch_bounds__(BLK) void k_twist(const float* __restrict__ W2, const float* __restrict__ W3,
                                               const float* __restrict__ W4, float* __restrict__ Wt2,
                                               float* __restrict__ Wt3, float* __restrict__ Wt4) {
    int t = blockIdx.x * BLK + threadIdx.x;
    if (t < 512) {                       // 32x16
        int co = t % 32, k = t / 32;
        Wt2[k * 32 + co] = W2[co * 16 + k];
    } else if (t < 512 + 1536) {         // 48x32
        int u = t - 512; int co = u % 48, k = u / 48;
        Wt3[k * 48 + co] = W3[co * 32 + k];
    } else if (t < 512 + 1536 + 3072) {  // 64x48
        int u = t - 2048; int co = u % 64, k = u / 64;
        Wt4[k * 64 + co] = W4[co * 48 + k];
    }
}

// partition edges into padded coarse buckets; packed = (col & 255) << 17 | row   (row < 2^17)
// LDS-staged: scatter into per-bucket LDS runs, then bucket-major coalesced flush.
__global__ __launch_bounds__(PBLK) void k_part(const int* __restrict__ row, const int* __restrict__ col,
                                               int* __restrict__ cursor, unsigned* __restrict__ bkt,
                                               int e, int nbk) {
    __shared__ int h[512];
    __shared__ int base_l[512];
    __shared__ int pfx[512];          // inclusive scan of h
    __shared__ int c2[512];
    __shared__ unsigned staged[PER_WG];   // 25.6 KB
    int tid = threadIdx.x;
    for (int i = tid; i < 512; i += PBLK) h[i] = 0;
    __syncthreads();
    int base = blockIdx.x * PER_WG;
    int end = min(e, base + PER_WG);
    for (int i = base + tid; i < end; i += PBLK) atomicAdd(&h[col[i] >> BSHIFT], 1);
    __syncthreads();
    for (int i = tid; i < 512; i += PBLK) {
        base_l[i] = (i < nbk && h[i]) ? atomicAdd(&cursor[i], h[i]) : 0;
        pfx[i] = h[i];
        c2[i] = 0;
    }
    __syncthreads();
#pragma unroll
    for (int d = 1; d < 512; d <<= 1) {
        int v = 0;
        if (tid < 512) { v = pfx[tid]; if (tid >= d) v += pfx[tid - d]; }
        __syncthreads();
        if (tid < 512) pfx[tid] = v;
        __syncthreads();
    }
    for (int i = base + tid; i < end; i += PBLK) {
        int c = col[i];
        int b = c >> BSHIFT;
        int slot = atomicAdd(&c2[b], 1);
        staged[pfx[b] - h[b] + slot] = ((unsigned)(c & (BSPAN - 1)) << 17) | (unsigned)row[i];
    }
    __syncthreads();
    int wid = tid >> 6, lane = tid & 63;
    constexpr int NW = PBLK >> 6;
    for (int b = wid; b < nbk; b += NW) {
        int L = h[b];
        if (!L) continue;
        int g = base_l[b], p = pfx[b] - L;
        for (int k = lane; k < L; k += 64) bkt[g + k] = staged[p + k];
    }
}

// one WG per bucket: LDS counting sort -> coalesced srow, colstart/cnt/dinv, and layer-1 xs3h
__global__ __launch_bounds__(BLK) void k_bucket(const unsigned* __restrict__ bkt, const int* __restrict__ cursor,
                                                const float* __restrict__ x,
                                                int* __restrict__ colstart, int* __restrict__ cntarr,
                                                int* __restrict__ srow, float* __restrict__ dinv,
                                                __half* __restrict__ xs3h, int n) {
    __shared__ int stage[CAPSLOT];   // 48 KB
    __shared__ int deg[BSPAN];
    __shared__ int pfx[BSPAN];
    int b = blockIdx.x;
    int eb = b * CAPSLOT;
    int ee = min(cursor[b], eb + CAPSLOT);
    int cnt = ee - eb;
    int n0 = b << BSHIFT;
    int nn = min(BSPAN, n - n0);
    for (int i = threadIdx.x; i < nn; i += BLK) deg[i] = 0;
    __syncthreads();
    for (int i = eb + threadIdx.x; i < ee; i += BLK) atomicAdd(&deg[bkt[i] >> 17], 1);
    __syncthreads();
    if (threadIdx.x == 0) {
        int acc = 0;
        for (int i = 0; i < nn; ++i) { pfx[i] = acc; acc += deg[i]; }
    }
    __syncthreads();
    for (int i = threadIdx.x; i < nn; i += BLK) {
        colstart[n0 + i] = eb + pfx[i];
        cntarr[n0 + i] = deg[i];
        float d = rsqrtf((float)(deg[i] + 1));   // +1 self-loop
        dinv[n0 + i] = d;
        const float* xp = x + (size_t)(n0 + i) * 3;
        __half2 h0 = __halves2half2(__float2half(d * xp[0]), __float2half(d * xp[1]));
        __half2 h1 = __halves2half2(__float2half(d * xp[2]), __float2half(0.0f));
        ((uint2*)xs3h)[n0 + i] = make_uint2(*(unsigned*)&h0, *(unsigned*)&h1);
    }
    __syncthreads();
    for (int i = eb + threadIdx.x; i < ee; i += BLK) {
        unsigned p = bkt[i];
        int s = atomicAdd(&pfx[p >> 17], 1);
        stage[s] = (int)(p & 0x1FFFFu);
    }
    __syncthreads();
    for (int i = threadIdx.x; i < cnt; i += BLK) srow[eb + i] = stage[i];  // coalesced
}

// fused layer 1: 3-ch fp16 agg (thread per node, 8B/edge) + 3->16 transform + fp16 prescaled output
__global__ __launch_bounds__(BLK) void k_agg3tf(const int* __restrict__ colstart, const int* __restrict__ cntarr,
                                                const int* __restrict__ srow, const uint2* __restrict__ xs3h,
                                                const float* __restrict__ dinv, const float* __restrict__ W,
                                                const float* __restrict__ bias, __half* __restrict__ xs_out, int n) {
    __shared__ float sW[48];
    __shared__ float sB[16];
    if (threadIdx.x < 48) sW[threadIdx.x] = W[threadIdx.x];
    if (threadIdx.x < 16) sB[threadIdx.x] = bias[threadIdx.x];
    __syncthreads();
    int node = blockIdx.x * BLK + threadIdx.x;
    if (node >= n) return;
    uint2 sv = xs3h[node];
    float2 s0 = __half22float2(*(__half2*)&sv.x);
    float2 s1 = __half22float2(*(__half2*)&sv.y);
    float a0 = s0.x, a1 = s0.y, a2 = s1.x;
    int jb = colstart[node], je = jb + cntarr[node];
    int j = jb;
    for (; j + 3 < je; j += 4) {
        int r0 = srow[j], r1 = srow[j + 1], r2 = srow[j + 2], r3 = srow[j + 3];
        uint2 v0 = xs3h[r0], v1 = xs3h[r1], v2 = xs3h[r2], v3 = xs3h[r3];
        float2 u0 = __half22float2(*(__half2*)&v0.x), u1 = __half22float2(*(__half2*)&v0.y);
        float2 w0 = __half22float2(*(__half2*)&v1.x), w1 = __half22float2(*(__half2*)&v1.y);
        float2 y0f = __half22float2(*(__half2*)&v2.x), y1f = __half22float2(*(__half2*)&v2.y);
        float2 z0 = __half22float2(*(__half2*)&v3.x), z1 = __half22float2(*(__half2*)&v3.y);
        a0 += (u0.x + w0.x) + (y0f.x + z0.x);
        a1 += (u0.y + w0.y) + (y0f.y + z0.y);
        a2 += (u1.x + w1.x) + (y1f.x + z1.x);
    }
    for (; j < je; ++j) {
        uint2 v = xs3h[srow[j]];
        float2 u0 = __half22float2(*(__half2*)&v.x), u1 = __half22float2(*(__half2*)&v.y);
        a0 += u0.x; a1 += u0.y; a2 += u1.x;
    }
    float d = dinv[node];
    float y0 = d * a0, y1 = d * a1, y2 = d * a2;
#pragma unroll
    for (int q = 0; q < 4; ++q) {
        float v[4];
#pragma unroll
        for (int jj = 0; jj < 4; ++jj) {
            int co = q * 4 + jj;
            float acc = sB[co] + y0 * sW[co * 3] + y1 * sW[co * 3 + 1] + y2 * sW[co * 3 + 2];
            v[jj] = d * fmaxf(acc, 0.0f);
        }
        __half2 h0 = __halves2half2(__float2half(v[0]), __float2half(v[1]));
        __half2 h1 = __halves2half2(__float2half(v[2]), __float2half(v[3]));
        uint2 u = make_uint2(*(unsigned*)&h0, *(unsigned*)&h1);
        ((uint2*)xs_out)[(size_t)node * 4 + q] = u;
    }
}

// fused mid/last layer: fp16 gather-agg (LPN lanes/node, 8-edge unroll) -> LDS y -> transform
// Wt is PRE-TRANSPOSED [Cin][Cout]. OMODE: 0 = fp32 out, 1 = fp16 prescaled (dinv*relu), 2 = fp16 relu.
template<int C, int LPN, int Cout, int OMODE>
__global__ __launch_bounds__(256) void k_aggtf(const int* __restrict__ colstart, const int* __restrict__ cntarr,
                                               const int* __restrict__ srow, const __half2* __restrict__ xs,
                                               const float* __restrict__ dinv, const float* __restrict__ Wt,
                                               const float* __restrict__ bias, void* __restrict__ outp, int n) {
    constexpr int TPB = 256;
    constexpr int HC = C / 2;
    constexpr int H2PL = HC / LPN;      // half2 per lane
    constexpr int NPB = TPB / LPN;      // nodes per block (32)
    constexpr int QPN = Cout / 4;
    constexpr int CP = C + 4;           // padded LDS row (bank rotation)
    __shared__ __align__(16) float yb[NPB][CP];
    __shared__ __align__(16) float smWt[C * Cout];
    __shared__ __align__(16) float smB[Cout];
    for (int idx = threadIdx.x; idx < C * Cout; idx += TPB) smWt[idx] = Wt[idx];  // coalesced copy
    if (threadIdx.x < Cout) smB[threadIdx.x] = bias[threadIdx.x];

    // ---- phase 1: aggregate into LDS ----
    int nl = threadIdx.x / LPN;
    int c0 = threadIdx.x % LPN;
    int node = blockIdx.x * NPB + nl;
    if (node < n) {
        float2 acc[H2PL];
        const __half2* self = xs + (size_t)node * HC + c0 * H2PL;
#pragma unroll
        for (int h = 0; h < H2PL; ++h) acc[h] = __half22float2(self[h]);
        int jb = colstart[node], je = jb + cntarr[node];
        int j = jb;
        for (; j + 7 < je; j += 8) {    // 8-edge unroll
            int r[8];
#pragma unroll
            for (int u = 0; u < 8; ++u) r[u] = srow[j + u];
#pragma unroll
            for (int u = 0; u < 8; ++u) {
                const __half2* p = xs + (size_t)r[u] * HC + c0 * H2PL;
#pragma unroll
                for (int h = 0; h < H2PL; ++h) {
                    float2 f = __half22float2(p[h]);
                    acc[h].x += f.x; acc[h].y += f.y;
                }
            }
        }
        for (; j < je; ++j) {
            const __half2* p = xs + (size_t)srow[j] * HC + c0 * H2PL;
#pragma unroll
            for (int h = 0; h < H2PL; ++h) {
                float2 f = __half22float2(p[h]);
                acc[h].x += f.x; acc[h].y += f.y;
            }
        }
        float d = dinv[node];
#pragma unroll
        for (int h = 0; h < H2PL; ++h) {
            *(float2*)&yb[nl][(c0 * H2PL + h) * 2] = make_float2(d * acc[h].x, d * acc[h].y);
        }
    }
    __syncthreads();

    // ---- phase 2: transform from LDS ----
    int base = blockIdx.x * NPB;
    for (int idx = threadIdx.x; idx < NPB * QPN; idx += TPB) {
        int nl2 = idx / QPN, q = idx % QPN;
        int nd = base + nl2;
        if (nd >= n) break;   // nd nondecreasing in idx
        const float* yr = yb[nl2];
        float4 bb = ((const float4*)smB)[q];
        float a0 = bb.x, a1 = bb.y, a2 = bb.z, a3 = bb.w;
        const float4* wt = (const float4*)smWt;
#pragma unroll
        for (int k = 0; k < C; ++k) {
            float yk = yr[k];
            float4 w = wt[k * QPN + q];
            a0 = fmaf(yk, w.x, a0); a1 = fmaf(yk, w.y, a1);
            a2 = fmaf(yk, w.z, a2); a3 = fmaf(yk, w.w, a3);
        }
        a0 = fmaxf(a0, 0.f); a1 = fmaxf(a1, 0.f); a2 = fmaxf(a2, 0.f); a3 = fmaxf(a3, 0.f);
        if constexpr (OMODE == 0) {
            ((float4*)outp)[(size_t)nd * QPN + q] = make_float4(a0, a1, a2, a3);
        } else {
            if constexpr (OMODE == 1) {
                float d = dinv[nd];
                a0 *= d; a1 *= d; a2 *= d; a3 *= d;
            }
            __half2 h0 = __halves2half2(__float2half(a0), __float2half(a1));
            __half2 h1 = __halves2half2(__float2half(a2), __float2half(a3));
            uint2 u = make_uint2(*(unsigned*)&h0, *(unsigned*)&h1);
            ((uint2*)outp)[(size_t)nd * QPN + q] = u;
        }
    }
}

// fused head: one block per graph — binary-search boundaries in sorted batch, pool fp16 H,
// then mlp1 (64ch) + mlp2 (10ch) entirely in-block.
__global__ __launch_bounds__(256) void k_head(const __half* __restrict__ H, const int* __restrict__ batch,
                                              int n, const float* __restrict__ L1w, const float* __restrict__ L1b,
                                              const float* __restrict__ L2w, const float* __restrict__ L2b,
                                              float* __restrict__ out) {
    int gr = blockIdx.x;
    int lo = 0, hi = n;
    while (lo < hi) { int mid = (lo + hi) >> 1; if (batch[mid] < gr) lo = mid + 1; else hi = mid; }
    int i0 = lo;
    hi = n;
    while (lo < hi) { int mid = (lo + hi) >> 1; if (batch[mid] < gr + 1) lo = mid + 1; else hi = mid; }
    int i1 = lo;
    int c = threadIdx.x & 63, s = threadIdx.x >> 6;
    float m = 0.0f;
    for (int i = i0 + s; i < i1; i += 4) m = fmaxf(m, __half2float(H[(size_t)i * 64 + c]));
    __shared__ float sm[256];
    __shared__ float g[64];
    __shared__ float g2[64];
    sm[threadIdx.x] = m;
    __syncthreads();
    if (s == 0) g[c] = fmaxf(fmaxf(sm[c], sm[64 + c]), fmaxf(sm[128 + c], sm[192 + c]));
    __syncthreads();
    if (threadIdx.x < 64) {
        const float* wsr = L1w + threadIdx.x * 64;
        float acc = L1b[threadIdx.x];
#pragma unroll
        for (int k = 0; k < 64; ++k) acc = fmaf(g[k], wsr[k], acc);
        g2[threadIdx.x] = fmaxf(acc, 0.0f);
    }
    __syncthreads();
    if (threadIdx.x < 10) {
        const float* wsr = L2w + threadIdx.x * 64;
        float acc = L2b[threadIdx.x];
#pragma unroll
        for (int k = 0; k < 64; ++k) acc = fmaf(g2[k], wsr[k], acc);
        out[gr * 10 + threadIdx.x] = acc;
    }
}

extern "C" void kernel_launch(void* const* d_in, const int* in_sizes, int n_in,
                              void* d_out, int out_size, void* d_ws, size_t ws_size,
                              hipStream_t stream) {
    const float* x     = (const float*)d_in[0];
    const int*   ei    = (const int*)d_in[1];
    const int*   batch = (const int*)d_in[2];
    const float *W1 = (const float*)d_in[4],  *b1 = (const float*)d_in[5];
    const float *W2 = (const float*)d_in[6],  *b2 = (const float*)d_in[7];
    const float *W3 = (const float*)d_in[8],  *b3 = (const float*)d_in[9];
    const float *W4 = (const float*)d_in[10], *b4 = (const float*)d_in[11];
    const float *L1w = (const float*)d_in[12], *L1b = (const float*)d_in[13];
    const float *L2w = (const float*)d_in[14], *L2b = (const float*)d_in[15];
    float* out = (float*)d_out;

    const int n  = in_sizes[0] / 3;   // 100000 (row ids fit 17 bits)
    const int e  = in_sizes[1] / 2;   // 3200000
    const int ng = 256;
    const int* row = ei;
    const int* col = ei + e;
    const int nbk = cdiv(n, BSPAN);   // 391 coarse buckets

    char* ws = (char*)d_ws;
    size_t off = 0;
    auto alloc = [&](size_t bytes) -> void* {
        void* p = ws + off;
        off += (bytes + 255) & ~(size_t)255;
        return p;
    };
    int*    colstart = (int*)alloc((size_t)n * 4);
    int*    cntarr   = (int*)alloc((size_t)n * 4);
    float*  dinv     = (float*)alloc((size_t)n * 4);
    int*    srow     = (int*)alloc((size_t)nbk * CAPSLOT * 4);   // 19.2 MB padded
    int*    cursor   = (int*)alloc(512 * 4);
    float*  Wt2      = (float*)alloc(512 * 4);
    float*  Wt3      = (float*)alloc(1536 * 4);
    float*  Wt4      = (float*)alloc(3072 * 4);
    __half* XS3H     = (__half*)alloc((size_t)n * 4 * 2);        // padded 4-half rows
    __half* XSA      = (__half*)alloc((size_t)n * 48 * 2);       // ping
    __half* XSB      = (__half*)alloc((size_t)n * 48 * 2);       // pong
    __half* H        = (__half*)alloc((size_t)n * 64 * 2);       // fp16 features for head
    unsigned* bkt    = (unsigned*)alloc((size_t)e * 4);          // 12.8 MB
    (void)ws_size; (void)n_in; (void)out_size;

    // ---- one-time weight transpose + CSR build (+ fused layer-1 input scaling) ----
    k_twist<<<cdiv(5120, BLK), BLK, 0, stream>>>(W2, W3, W4, Wt2, Wt3, Wt4);
    k_initcur<<<cdiv(nbk, BLK), BLK, 0, stream>>>(cursor, nbk);
    k_part<<<cdiv(e, PER_WG), PBLK, 0, stream>>>(row, col, cursor, bkt, e, nbk);
    k_bucket<<<nbk, BLK, 0, stream>>>(bkt, cursor, x, colstart, cntarr, srow, dinv, XS3H, n);

    // ---- layer 1: 3 -> 16 (fp16 8B/edge gather, fused) ----
    k_agg3tf<<<cdiv(n, BLK), BLK, 0, stream>>>(colstart, cntarr, srow, (const uint2*)XS3H, dinv, W1, b1, XSA, n);

    // ---- layer 2: 16 -> 32 (fused, XSA -> XSB) ----
    k_aggtf<16, 8, 32, 1><<<cdiv(n, 32), 256, 0, stream>>>(colstart, cntarr, srow,
        (const __half2*)XSA, dinv, Wt2, b2, XSB, n);

    // ---- layer 3: 32 -> 48 (fused, XSB -> XSA) ----
    k_aggtf<32, 8, 48, 1><<<cdiv(n, 32), 256, 0, stream>>>(colstart, cntarr, srow,
        (const __half2*)XSB, dinv, Wt3, b3, XSA, n);

    // ---- layer 4: 48 -> 64 (fused, XSA -> fp16 H) ----
    k_aggtf<48, 8, 64, 2><<<cdiv(n, 32), 256, 0, stream>>>(colstart, cntarr, srow,
        (const __half2*)XSA, dinv, Wt4, b4, H, n);

    // ---- fused head: pool + MLP (one block per graph) ----
    k_head<<<ng, 256, 0, stream>>>(H, batch, n, L1w, L1b, L2w, L2b, out);
}